// Round 11
// baseline (363.854 us; speedup 1.0000x reference)
//
#include <hip/hip_runtime.h>

#define N_NODES 50000
#define N_EDGES 800000
#define HID 128
#define OUT_CH 64
#define LDA 264   // LDS A-tile row stride in bf16 elems (256 + 8 pad)
#define SCAN_BLOCKS 196  // ceil(50000/256)
#define BSHIFT 6
#define NBUCKET ((N_NODES + 63) >> BSHIFT)   // 782

typedef __attribute__((ext_vector_type(8))) short bf16x8;
typedef __attribute__((ext_vector_type(4))) float f32x4;

__device__ __forceinline__ float bf2f(unsigned int bits16) {
    return __uint_as_float(bits16 << 16);
}
__device__ __forceinline__ unsigned short f2bf(float f) {
    unsigned int u = __float_as_uint(f);
    u = (u + 0x7fffu + ((u >> 16) & 1u)) >> 16;
    return (unsigned short)u;
}
__device__ __forceinline__ void acc_u4(float* a, uint4 v) {
    a[0] += bf2f(v.x & 0xffffu); a[1] += bf2f(v.x >> 16);
    a[2] += bf2f(v.y & 0xffffu); a[3] += bf2f(v.y >> 16);
    a[4] += bf2f(v.z & 0xffffu); a[5] += bf2f(v.z >> 16);
    a[6] += bf2f(v.w & 0xffffu); a[7] += bf2f(v.w >> 16);
}

// ---------------- convert x -> bf16 [N][128] ----------------
__global__ __launch_bounds__(256) void convert_x_kernel(
    const float* __restrict__ x, unsigned short* __restrict__ xb)
{
    int gid = blockIdx.x * 256 + threadIdx.x;     // over N*32
    int node = gid >> 5, c4 = gid & 31;
    float4 v = reinterpret_cast<const float4*>(x + (size_t)node * HID)[c4];
    unsigned short* o = xb + (size_t)node * HID + c4 * 4;
    o[0] = f2bf(v.x); o[1] = f2bf(v.y); o[2] = f2bf(v.z); o[3] = f2bf(v.w);
}

// ---------------- swizzle weights into MFMA fragment order ----------------
__global__ __launch_bounds__(256) void swizzle_w_kernel(
    const float* __restrict__ Wl1, const float* __restrict__ Wr1,
    const float* __restrict__ Wl2, const float* __restrict__ Wr2,
    const float* __restrict__ Wout,
    unsigned short* __restrict__ w1s, unsigned short* __restrict__ w2s,
    unsigned short* __restrict__ wos)
{
    int fid = blockIdx.x * 256 + threadIdx.x;   // 0..9215
    if (fid < 8192) {
        int layer = fid >> 12;
        int r = fid & 4095;
        int lane = r & 63, ks = (r >> 6) & 7, t = r >> 9;
        int col = t * 16 + (lane & 15);
        int kb = ks * 32 + (lane >> 4) * 8;
        const float* Wl = layer ? Wl2 : Wl1;
        const float* Wr = layer ? Wr2 : Wr1;
        unsigned short* o = (layer ? w2s : w1s) + (size_t)r * 8;
        #pragma unroll
        for (int j = 0; j < 8; ++j) {
            int k = kb + j;
            float v = (k < 128) ? Wl[(size_t)col * 128 + k] : Wr[(size_t)col * 128 + (k - 128)];
            o[j] = f2bf(v);
        }
    } else if (fid < 9216) {
        int r = fid - 8192;
        int lane = r & 63, ks = (r >> 6) & 3, t = r >> 8;
        int col = t * 16 + (lane & 15);
        int kb = ks * 32 + (lane >> 4) * 8;
        unsigned short* o = wos + (size_t)r * 8;
        #pragma unroll
        for (int j = 0; j < 8; ++j)
            o[j] = f2bf(Wout[(size_t)col * 128 + kb + j]);
    }
}

// ---------------- degree histogram ----------------
__global__ void hist_kernel(const int* __restrict__ dst, int* __restrict__ cnt) {
    int e = blockIdx.x * blockDim.x + threadIdx.x;
    if (e < N_EDGES) atomicAdd(&cnt[dst[e]], 1);
}

// ---------------- 3-phase exclusive scan of cnt ----------------
__global__ __launch_bounds__(256) void scanA_kernel(const int* __restrict__ cnt,
                                                    int* __restrict__ partial) {
    const int tid = threadIdx.x;
    const int i = blockIdx.x * 256 + tid;
    int v = (i < N_NODES) ? cnt[i] : 0;
    const int lane = tid & 63, wave = tid >> 6;
    int incl = v;
    #pragma unroll
    for (int off = 1; off < 64; off <<= 1) {
        int t = __shfl_up(incl, off);
        if (lane >= off) incl += t;
    }
    __shared__ int wsum[4];
    if (lane == 63) wsum[wave] = incl;
    __syncthreads();
    if (tid == 0) partial[blockIdx.x] = wsum[0] + wsum[1] + wsum[2] + wsum[3];
}

__global__ __launch_bounds__(256) void scanB_kernel(int* __restrict__ partial) {
    const int tid = threadIdx.x;
    int v = (tid < SCAN_BLOCKS) ? partial[tid] : 0;
    const int lane = tid & 63, wave = tid >> 6;
    int incl = v;
    #pragma unroll
    for (int off = 1; off < 64; off <<= 1) {
        int t = __shfl_up(incl, off);
        if (lane >= off) incl += t;
    }
    __shared__ int wsum[4];
    if (lane == 63) wsum[wave] = incl;
    __syncthreads();
    int base = 0;
    if (wave > 0) base += wsum[0];
    if (wave > 1) base += wsum[1];
    if (wave > 2) base += wsum[2];
    if (tid < SCAN_BLOCKS) partial[tid] = base + incl - v;   // exclusive
}

// scanC also seeds the bucket cursors: bcur[b] = row_ptr[b<<BSHIFT]
__global__ __launch_bounds__(256) void scanC_kernel(int* __restrict__ cnt,
                                                    const int* __restrict__ partial,
                                                    int* __restrict__ row_ptr,
                                                    int* __restrict__ bcur) {
    const int tid = threadIdx.x;
    const int i = blockIdx.x * 256 + tid;
    int v = (i < N_NODES) ? cnt[i] : 0;
    const int lane = tid & 63, wave = tid >> 6;
    int incl = v;
    #pragma unroll
    for (int off = 1; off < 64; off <<= 1) {
        int t = __shfl_up(incl, off);
        if (lane >= off) incl += t;
    }
    __shared__ int wsum[4];
    if (lane == 63) wsum[wave] = incl;
    __syncthreads();
    int base = partial[blockIdx.x];
    if (wave > 0) base += wsum[0];
    if (wave > 1) base += wsum[1];
    if (wave > 2) base += wsum[2];
    const int pre = base + incl - v;
    if (i < N_NODES) {
        cnt[i] = pre;                  // fill cursor
        row_ptr[i + 1] = pre + v;
        if ((i & 63) == 0) bcur[i >> BSHIFT] = pre;   // bucket staging cursor
    }
    if (i == 0) row_ptr[0] = 0;
}

// ---------------- two-pass bucketed fill ----------------
// Pass A: scatter (src,dst) pairs into dst>>6 buckets (sequential within bucket)
__global__ void fillA_kernel(const int* __restrict__ src, const int* __restrict__ dst,
                             int* __restrict__ bcur, uint2* __restrict__ epair) {
    int e = blockIdx.x * blockDim.x + threadIdx.x;
    if (e < N_EDGES) {
        int d = dst[e];
        int p = atomicAdd(&bcur[d >> BSHIFT], 1);
        epair[p] = make_uint2((unsigned)src[e], (unsigned)d);
    }
}
// Pass B: linear read of bucketed pairs; final scatter hits a <=4KB window per bucket
__global__ void fillB_kernel(const uint2* __restrict__ epair,
                             int* __restrict__ cursor, int* __restrict__ esrc) {
    int e = blockIdx.x * blockDim.x + threadIdx.x;
    if (e < N_EDGES) {
        uint2 pr = epair[e];
        int q = atomicAdd(&cursor[pr.y], 1);
        esrc[q] = (int)pr.x;
    }
}

// ---------------- standalone persistent gather: no LDS, no barriers ----------------
__global__ __launch_bounds__(256) void gather_kernel(
    const unsigned short* __restrict__ feat,
    const int* __restrict__ row_ptr, const int* __restrict__ esrc,
    unsigned short* __restrict__ agg)
{
    const int tid = threadIdx.x;
    const int wave = tid >> 6, lane = tid & 63;
    const int g = lane >> 4, c = lane & 15;
    const int gw0 = blockIdx.x * 4 + wave;
    const int NW = gridDim.x * 4;
    const int NGROUP = N_NODES / 4;   // 12500

    for (int grp = gw0; grp < NGROUP; grp += NW) {
        const int base = grp * 4;
        int beg[4], deg[4], ids[4];
        int rp0 = row_ptr[base];
        #pragma unroll
        for (int j = 0; j < 4; ++j) {
            int rp1 = row_ptr[base + j + 1];
            beg[j] = rp0; deg[j] = rp1 - rp0; rp0 = rp1;
        }
        #pragma unroll
        for (int j = 0; j < 4; ++j) {
            int idx = beg[j] + c;
            idx = (idx < N_EDGES) ? idx : (N_EDGES - 1);
            ids[j] = esrc[idx];
        }

        float acc[4][8];
        #pragma unroll
        for (int j = 0; j < 4; ++j)
            #pragma unroll
            for (int k = 0; k < 8; ++k) acc[j][k] = 0.0f;

        #pragma unroll
        for (int jp = 0; jp < 2; ++jp) {
            uint4 v[2][4];
            #pragma unroll
            for (int jj = 0; jj < 2; ++jj) {
                const int j = jp * 2 + jj;
                #pragma unroll
                for (int b = 0; b < 4; ++b) {
                    int s = __shfl(ids[j], b * 4 + g);
                    v[jj][b] = *reinterpret_cast<const uint4*>(feat + (size_t)s * HID + c * 8);
                }
            }
            #pragma unroll
            for (int jj = 0; jj < 2; ++jj) {
                const int j = jp * 2 + jj;
                #pragma unroll
                for (int b = 0; b < 4; ++b) {
                    uint4 vv = v[jj][b];
                    if (b * 4 + g >= deg[j]) vv = make_uint4(0u, 0u, 0u, 0u);
                    acc_u4(acc[j], vv);
                }
            }
            #pragma unroll
            for (int jj = 0; jj < 2; ++jj) {
                const int j = jp * 2 + jj;
                const int last = beg[j] + deg[j] - 1;
                for (int e0 = 16; e0 < deg[j]; e0 += 16) {
                    int idx = beg[j] + e0 + c;
                    int id2 = esrc[(idx < last) ? idx : last];
                    uint4 w[4];
                    #pragma unroll
                    for (int b = 0; b < 4; ++b) {
                        int s = __shfl(id2, b * 4 + g);
                        w[b] = *reinterpret_cast<const uint4*>(feat + (size_t)s * HID + c * 8);
                    }
                    #pragma unroll
                    for (int b = 0; b < 4; ++b) {
                        uint4 vv = w[b];
                        if (e0 + b * 4 + g >= deg[j]) vv = make_uint4(0u, 0u, 0u, 0u);
                        acc_u4(acc[j], vv);
                    }
                }
            }
        }

        #pragma unroll
        for (int j = 0; j < 4; ++j) {
            const float scale = 1.0f / fmaxf((float)deg[j], 1.0f);
            float r[8];
            #pragma unroll
            for (int k = 0; k < 8; ++k) {
                float t = acc[j][k];
                t += __shfl_xor(t, 16);
                t += __shfl_xor(t, 32);
                r[k] = t * scale;
            }
            if (g == 0) {
                uint4 pk;
                pk.x = (unsigned)f2bf(r[0]) | ((unsigned)f2bf(r[1]) << 16);
                pk.y = (unsigned)f2bf(r[2]) | ((unsigned)f2bf(r[3]) << 16);
                pk.z = (unsigned)f2bf(r[4]) | ((unsigned)f2bf(r[5]) << 16);
                pk.w = (unsigned)f2bf(r[6]) | ((unsigned)f2bf(r[7]) << 16);
                *reinterpret_cast<uint4*>(agg + (size_t)(base + j) * HID + c * 8) = pk;
            }
        }
    }
}

// ---------------- streaming SAGE GEMM (fragment-ordered weights) ----------------
__global__ __launch_bounds__(256) void sage_gemm_kernel(
    const unsigned short* __restrict__ aggIn,   // [N][128] mean-agg bf16
    const unsigned short* __restrict__ selfIn,  // [N][128] bf16
    const unsigned short* __restrict__ wsz,     // fragment-ordered [8][8][64][8]
    const float* __restrict__ bias,
    unsigned short* __restrict__ Hout, int relu)
{
    __shared__ unsigned short sA[16 * LDA];
    const int tid = threadIdx.x;
    const int wave = tid >> 6, lane = tid & 63;
    const int m0 = blockIdx.x * 16;

    {
        int r = tid >> 4, cc = tid & 15;
        *reinterpret_cast<uint4*>(&sA[r * LDA + cc * 8]) =
            reinterpret_cast<const uint4*>(aggIn + (size_t)(m0 + r) * HID)[cc];
        *reinterpret_cast<uint4*>(&sA[r * LDA + 128 + cc * 8]) =
            reinterpret_cast<const uint4*>(selfIn + (size_t)(m0 + r) * HID)[cc];
    }
    __syncthreads();

    const int l15 = lane & 15, lq = lane >> 4;
    bf16x8 bfrag[2][8];
    #pragma unroll
    for (int nt = 0; nt < 2; ++nt) {
        const unsigned short* wb = wsz + ((size_t)(wave * 2 + nt) * 8) * 64 * 8 + lane * 8;
        #pragma unroll
        for (int ks = 0; ks < 8; ++ks)
            bfrag[nt][ks] = *reinterpret_cast<const bf16x8*>(wb + (size_t)ks * 64 * 8);
    }
    f32x4 acc0 = {0.f, 0.f, 0.f, 0.f}, acc1 = {0.f, 0.f, 0.f, 0.f};
    #pragma unroll
    for (int ks = 0; ks < 8; ++ks) {
        bf16x8 af = *reinterpret_cast<const bf16x8*>(&sA[l15 * LDA + ks * 32 + lq * 8]);
        acc0 = __builtin_amdgcn_mfma_f32_16x16x32_bf16(af, bfrag[0][ks], acc0, 0, 0, 0);
        acc1 = __builtin_amdgcn_mfma_f32_16x16x32_bf16(af, bfrag[1][ks], acc1, 0, 0, 0);
    }
    const int n0 = wave * 32;
    #pragma unroll
    for (int nt = 0; nt < 2; ++nt) {
        const f32x4 a = nt ? acc1 : acc0;
        const int col = n0 + nt * 16 + l15;
        const float bv = bias[col];
        #pragma unroll
        for (int r = 0; r < 4; ++r) {
            float v = a[r] + bv;
            if (relu) v = fmaxf(v, 0.0f);
            Hout[(size_t)(m0 + lq * 4 + r) * HID + col] = f2bf(v);
        }
    }
}

// ---------------- layer-2 GEMM + MFMA head + log_softmax ----------------
__global__ __launch_bounds__(256) void final_gemm_kernel(
    const unsigned short* __restrict__ aggIn,   // [N][128] mean-agg of h1
    const unsigned short* __restrict__ selfIn,  // h1 [N][128]
    const unsigned short* __restrict__ wsz2,    // layer2 fragment-ordered
    const float* __restrict__ bl2,
    const unsigned short* __restrict__ wos,     // Wout fragment-ordered [4][4][64][8]
    const float* __restrict__ bout,
    float* __restrict__ out)
{
    __shared__ unsigned short sA[16 * LDA];     // 8448 B
    __shared__ float sL[16][OUT_CH];            // 4096 B
    const int tid = threadIdx.x;
    const int wave = tid >> 6, lane = tid & 63;
    const int m0 = blockIdx.x * 16;

    {
        int r = tid >> 4, cc = tid & 15;
        *reinterpret_cast<uint4*>(&sA[r * LDA + cc * 8]) =
            reinterpret_cast<const uint4*>(aggIn + (size_t)(m0 + r) * HID)[cc];
        *reinterpret_cast<uint4*>(&sA[r * LDA + 128 + cc * 8]) =
            reinterpret_cast<const uint4*>(selfIn + (size_t)(m0 + r) * HID)[cc];
    }
    __syncthreads();

    const int l15 = lane & 15, lq = lane >> 4;
    bf16x8 bfrag[2][8];
    #pragma unroll
    for (int nt = 0; nt < 2; ++nt) {
        const unsigned short* wb = wsz2 + ((size_t)(wave * 2 + nt) * 8) * 64 * 8 + lane * 8;
        #pragma unroll
        for (int ks = 0; ks < 8; ++ks)
            bfrag[nt][ks] = *reinterpret_cast<const bf16x8*>(wb + (size_t)ks * 64 * 8);
    }
    f32x4 acc0 = {0.f, 0.f, 0.f, 0.f}, acc1 = {0.f, 0.f, 0.f, 0.f};
    #pragma unroll
    for (int ks = 0; ks < 8; ++ks) {
        bf16x8 af = *reinterpret_cast<const bf16x8*>(&sA[l15 * LDA + ks * 32 + lq * 8]);
        acc0 = __builtin_amdgcn_mfma_f32_16x16x32_bf16(af, bfrag[0][ks], acc0, 0, 0, 0);
        acc1 = __builtin_amdgcn_mfma_f32_16x16x32_bf16(af, bfrag[1][ks], acc1, 0, 0, 0);
    }
    __syncthreads();   // all waves done reading sA before h2 overwrite

    // h2 (bf16) -> sA[row][0..127]
    const int n0 = wave * 32;
    #pragma unroll
    for (int nt = 0; nt < 2; ++nt) {
        const f32x4 a = nt ? acc1 : acc0;
        const int col = n0 + nt * 16 + l15;
        const float bv = bl2[col];
        #pragma unroll
        for (int r = 0; r < 4; ++r)
            sA[(lq * 4 + r) * LDA + col] = f2bf(a[r] + bv);
    }
    __syncthreads();

    // head via MFMA: logits[16][64]; wave covers cols wave*16..+15
    {
        f32x4 hacc = {0.f, 0.f, 0.f, 0.f};
        #pragma unroll
        for (int ks = 0; ks < 4; ++ks) {
            bf16x8 af = *reinterpret_cast<const bf16x8*>(&sA[l15 * LDA + ks * 32 + lq * 8]);
            bf16x8 bf = *reinterpret_cast<const bf16x8*>(
                wos + ((size_t)(wave * 4 + ks)) * 64 * 8 + lane * 8);
            hacc = __builtin_amdgcn_mfma_f32_16x16x32_bf16(af, bf, hacc, 0, 0, 0);
        }
        const int col = wave * 16 + l15;
        const float bo = bout[col];
        #pragma unroll
        for (int r = 0; r < 4; ++r)
            sL[lq * 4 + r][col] = hacc[r] + bo;
    }
    __syncthreads();

    // log_softmax: one wave per row
    for (int r = wave; r < 16; r += 4) {
        float v = sL[r][lane];
        float m = v;
        for (int off = 32; off; off >>= 1) m = fmaxf(m, __shfl_xor(m, off));
        float ex = expf(v - m);
        float s = ex;
        for (int off = 32; off; off >>= 1) s += __shfl_xor(s, off);
        out[(size_t)(m0 + r) * OUT_CH + lane] = v - m - logf(s);
    }
}

extern "C" void kernel_launch(void* const* d_in, const int* in_sizes, int n_in,
                              void* d_out, int out_size, void* d_ws, size_t ws_size,
                              hipStream_t stream) {
    const float* x    = (const float*)d_in[0];
    const int*   edge = (const int*)d_in[1];
    const int*   src  = edge;
    const int*   dst  = edge + N_EDGES;
    const float* Wl1  = (const float*)d_in[2];
    const float* bl1  = (const float*)d_in[3];
    const float* Wr1  = (const float*)d_in[4];
    const float* Wl2  = (const float*)d_in[5];
    const float* bl2  = (const float*)d_in[6];
    const float* Wr2  = (const float*)d_in[7];
    const float* Wout = (const float*)d_in[8];
    const float* bout = (const float*)d_in[9];
    float* out = (float*)d_out;

    char* ws = (char*)d_ws;
    const size_t featBytes = (size_t)N_NODES * HID * 2;          // 12.8 MB
    unsigned short* xb  = (unsigned short*)ws;
    unsigned short* h1  = (unsigned short*)(ws + featBytes);
    unsigned short* agg = (unsigned short*)(ws + 2 * featBytes);
    char* p = ws + 3 * featBytes;
    int* cnt     = (int*)p;   p += (size_t)N_NODES * 4;
    int* row_ptr = (int*)p;   p += (size_t)(N_NODES + 1) * 4 + 252;
    int* partial = (int*)p;   p += 1024;
    int* bcur    = (int*)p;   p += (size_t)NBUCKET * 4 + 72;     // keep 16B align
    int* esrc    = (int*)p;   p += (size_t)N_EDGES * 4;
    uint2* epair = (uint2*)p; p += (size_t)N_EDGES * 8;
    unsigned short* w1s = (unsigned short*)p;  p += 128 * 256 * 2;   // 64 KB
    unsigned short* w2s = (unsigned short*)p;  p += 128 * 256 * 2;   // 64 KB
    unsigned short* wos = (unsigned short*)p;                        // 16 KB

    hipMemsetAsync(cnt, 0, (size_t)N_NODES * sizeof(int), stream);
    hist_kernel<<<N_EDGES / 256, 256, 0, stream>>>(dst, cnt);
    convert_x_kernel<<<N_NODES * 32 / 256, 256, 0, stream>>>(x, xb);
    swizzle_w_kernel<<<36, 256, 0, stream>>>(Wl1, Wr1, Wl2, Wr2, Wout, w1s, w2s, wos);
    scanA_kernel<<<SCAN_BLOCKS, 256, 0, stream>>>(cnt, partial);
    scanB_kernel<<<1, 256, 0, stream>>>(partial);
    scanC_kernel<<<SCAN_BLOCKS, 256, 0, stream>>>(cnt, partial, row_ptr, bcur);
    fillA_kernel<<<N_EDGES / 256, 256, 0, stream>>>(src, dst, bcur, epair);
    fillB_kernel<<<N_EDGES / 256, 256, 0, stream>>>(epair, cnt, esrc);

    gather_kernel<<<2048, 256, 0, stream>>>(xb, row_ptr, esrc, agg);
    sage_gemm_kernel<<<N_NODES / 16, 256, 0, stream>>>(agg, xb, w1s, bl1, h1, 1);
    gather_kernel<<<2048, 256, 0, stream>>>(h1, row_ptr, esrc, agg);
    final_gemm_kernel<<<N_NODES / 16, 256, 0, stream>>>(agg, h1, w2s, bl2,
                                                        wos, bout, out);
}

// Round 12
// 133.097 us; speedup vs baseline: 2.7338x; 2.7338x over previous
//
#include <hip/hip_runtime.h>

#define N_NODES 50000
#define N_EDGES 800000
#define HID 128
#define OUT_CH 64
#define LDA 264   // LDS A-tile row stride in bf16 elems (256 + 8 pad)
#define BSHIFT 6
#define NBUCKET ((N_NODES + 63) >> BSHIFT)   // 782
#define NCHUNK 256
#define CHUNK_E (N_EDGES / NCHUNK)           // 3125
#define BCAP 2560                            // LDS bucket capacity (mean 1024, +48 sigma)

typedef __attribute__((ext_vector_type(8))) short bf16x8;
typedef __attribute__((ext_vector_type(4))) float f32x4;

__device__ __forceinline__ float bf2f(unsigned int bits16) {
    return __uint_as_float(bits16 << 16);
}
__device__ __forceinline__ unsigned short f2bf(float f) {
    unsigned int u = __float_as_uint(f);
    u = (u + 0x7fffu + ((u >> 16) & 1u)) >> 16;
    return (unsigned short)u;
}
__device__ __forceinline__ void acc_u4(float* a, uint4 v) {
    a[0] += bf2f(v.x & 0xffffu); a[1] += bf2f(v.x >> 16);
    a[2] += bf2f(v.y & 0xffffu); a[3] += bf2f(v.y >> 16);
    a[4] += bf2f(v.z & 0xffffu); a[5] += bf2f(v.z >> 16);
    a[6] += bf2f(v.w & 0xffffu); a[7] += bf2f(v.w >> 16);
}

// ---------------- convert x -> bf16 [N][128] ----------------
__global__ __launch_bounds__(256) void convert_x_kernel(
    const float* __restrict__ x, unsigned short* __restrict__ xb)
{
    int gid = blockIdx.x * 256 + threadIdx.x;     // over N*32
    int node = gid >> 5, c4 = gid & 31;
    float4 v = reinterpret_cast<const float4*>(x + (size_t)node * HID)[c4];
    unsigned short* o = xb + (size_t)node * HID + c4 * 4;
    o[0] = f2bf(v.x); o[1] = f2bf(v.y); o[2] = f2bf(v.z); o[3] = f2bf(v.w);
}

// ---------------- swizzle weights into MFMA fragment order ----------------
__global__ __launch_bounds__(256) void swizzle_w_kernel(
    const float* __restrict__ Wl1, const float* __restrict__ Wr1,
    const float* __restrict__ Wl2, const float* __restrict__ Wr2,
    const float* __restrict__ Wout,
    unsigned short* __restrict__ w1s, unsigned short* __restrict__ w2s,
    unsigned short* __restrict__ wos)
{
    int fid = blockIdx.x * 256 + threadIdx.x;   // 0..9215
    if (fid < 8192) {
        int layer = fid >> 12;
        int r = fid & 4095;
        int lane = r & 63, ks = (r >> 6) & 7, t = r >> 9;
        int col = t * 16 + (lane & 15);
        int kb = ks * 32 + (lane >> 4) * 8;
        const float* Wl = layer ? Wl2 : Wl1;
        const float* Wr = layer ? Wr2 : Wr1;
        unsigned short* o = (layer ? w2s : w1s) + (size_t)r * 8;
        #pragma unroll
        for (int j = 0; j < 8; ++j) {
            int k = kb + j;
            float v = (k < 128) ? Wl[(size_t)col * 128 + k] : Wr[(size_t)col * 128 + (k - 128)];
            o[j] = f2bf(v);
        }
    } else if (fid < 9216) {
        int r = fid - 8192;
        int lane = r & 63, ks = (r >> 6) & 3, t = r >> 8;
        int col = t * 16 + (lane & 15);
        int kb = ks * 32 + (lane >> 4) * 8;
        unsigned short* o = wos + (size_t)r * 8;
        #pragma unroll
        for (int j = 0; j < 8; ++j)
            o[j] = f2bf(Wout[(size_t)col * 128 + kb + j]);
    }
}

// ---------------- stage 1: per-chunk bucket histogram (LDS counters) ----------------
__global__ __launch_bounds__(256) void histb_kernel(const int* __restrict__ dst,
                                                    int* __restrict__ histg) {
    __shared__ int h[NBUCKET];
    for (int i = threadIdx.x; i < NBUCKET; i += 256) h[i] = 0;
    __syncthreads();
    const int e0 = blockIdx.x * CHUNK_E;
    for (int i = threadIdx.x; i < CHUNK_E; i += 256)
        atomicAdd(&h[dst[e0 + i] >> BSHIFT], 1);
    __syncthreads();
    for (int i = threadIdx.x; i < NBUCKET; i += 256)
        histg[i * NCHUNK + blockIdx.x] = h[i];
}

// ---------------- stage 2: exclusive scan over histg (bucket-major, 200192 elems) ----------------
__global__ __launch_bounds__(256) void scanA2_kernel(const int* __restrict__ histg,
                                                     int* __restrict__ partial) {
    const int tid = threadIdx.x;
    int v = histg[blockIdx.x * 256 + tid];
    const int lane = tid & 63, wave = tid >> 6;
    int incl = v;
    #pragma unroll
    for (int off = 1; off < 64; off <<= 1) {
        int t = __shfl_up(incl, off);
        if (lane >= off) incl += t;
    }
    __shared__ int wsum[4];
    if (lane == 63) wsum[wave] = incl;
    __syncthreads();
    if (tid == 0) partial[blockIdx.x] = wsum[0] + wsum[1] + wsum[2] + wsum[3];
}

__global__ __launch_bounds__(256) void scanB2_kernel(int* __restrict__ partial) {
    const int tid = threadIdx.x;
    int vals[4]; int sum = 0;
    #pragma unroll
    for (int j = 0; j < 4; ++j) {
        int idx = tid * 4 + j;
        vals[j] = (idx < NBUCKET) ? partial[idx] : 0;
        sum += vals[j];
    }
    const int lane = tid & 63, wave = tid >> 6;
    int incl = sum;
    #pragma unroll
    for (int off = 1; off < 64; off <<= 1) {
        int t = __shfl_up(incl, off);
        if (lane >= off) incl += t;
    }
    __shared__ int wsum[4];
    if (lane == 63) wsum[wave] = incl;
    __syncthreads();
    int base = 0;
    if (wave > 0) base += wsum[0];
    if (wave > 1) base += wsum[1];
    if (wave > 2) base += wsum[2];
    int run = base + incl - sum;
    #pragma unroll
    for (int j = 0; j < 4; ++j) {
        int idx = tid * 4 + j;
        if (idx < NBUCKET) { int c = vals[j]; partial[idx] = run; run += c; }
    }
}

__global__ __launch_bounds__(256) void scanC2_kernel(int* __restrict__ histg,
                                                     const int* __restrict__ partial) {
    const int tid = threadIdx.x;
    const int i = blockIdx.x * 256 + tid;
    int v = histg[i];
    const int lane = tid & 63, wave = tid >> 6;
    int incl = v;
    #pragma unroll
    for (int off = 1; off < 64; off <<= 1) {
        int t = __shfl_up(incl, off);
        if (lane >= off) incl += t;
    }
    __shared__ int wsum[4];
    if (lane == 63) wsum[wave] = incl;
    __syncthreads();
    int base = partial[blockIdx.x];
    if (wave > 0) base += wsum[0];
    if (wave > 1) base += wsum[1];
    if (wave > 2) base += wsum[2];
    histg[i] = base + incl - v;     // exclusive offset for (bucket, chunk)
}

// ---------------- stage 3: bin edges into bucket regions (LDS cursors, no global atomics) ----------------
__global__ __launch_bounds__(256) void binA_kernel(
    const int* __restrict__ src, const int* __restrict__ dst,
    const int* __restrict__ obase, unsigned* __restrict__ epack)
{
    __shared__ int cur[NBUCKET];
    for (int i = threadIdx.x; i < NBUCKET; i += 256)
        cur[i] = obase[i * NCHUNK + blockIdx.x];
    __syncthreads();
    const int e0 = blockIdx.x * CHUNK_E;
    for (int i = threadIdx.x; i < CHUNK_E; i += 256) {
        int d = dst[e0 + i];
        int p = atomicAdd(&cur[d >> BSHIFT], 1);
        epack[p] = (unsigned)src[e0 + i] | ((unsigned)(d & 63) << 16);
    }
}

// ---------------- stage 4: in-LDS sort of each bucket -> esrc (ushort) + row_ptr ----------------
__global__ __launch_bounds__(256) void bucket_sort_kernel(
    const unsigned* __restrict__ epack, const int* __restrict__ obase,
    int* __restrict__ row_ptr, unsigned short* __restrict__ esrc)
{
    __shared__ unsigned lpack[BCAP];
    __shared__ unsigned short lout[BCAP];
    __shared__ int deg[64], cur[64];
    const int b = blockIdx.x;
    const int tid = threadIdx.x;
    const int regBeg = obase[b * NCHUNK];
    const int regEnd = (b + 1 < NBUCKET) ? obase[(b + 1) * NCHUNK] : N_EDGES;
    const int cnt = regEnd - regBeg;

    if (tid < 64) deg[tid] = 0;
    __syncthreads();
    for (int i = tid; i < cnt; i += 256) {
        unsigned p = epack[regBeg + i];
        if (i < BCAP) lpack[i] = p;
        atomicAdd(&deg[(p >> 16) & 63], 1);
    }
    __syncthreads();
    if (tid < 64) {
        int v = deg[tid];
        int incl = v;
        #pragma unroll
        for (int off = 1; off < 64; off <<= 1) {
            int t = __shfl_up(incl, off);
            if (tid >= off) incl += t;
        }
        int pre = incl - v;
        cur[tid] = pre;
        int node = b * 64 + tid;
        if (node < N_NODES) row_ptr[node] = regBeg + pre;
    }
    if (b == NBUCKET - 1 && tid == 0) row_ptr[N_NODES] = N_EDGES;
    __syncthreads();
    for (int i = tid; i < cnt; i += 256) {
        unsigned p = (i < BCAP) ? lpack[i] : epack[regBeg + i];
        int q = atomicAdd(&cur[(p >> 16) & 63], 1);
        unsigned short s = (unsigned short)(p & 0xffffu);
        if (q < BCAP) lout[q] = s;
        else esrc[regBeg + q] = s;     // overflow path (statistically never)
    }
    __syncthreads();
    const int lim = (cnt < BCAP) ? cnt : BCAP;
    for (int i = tid; i < lim; i += 256)
        esrc[regBeg + i] = lout[i];
}

// ---------------- standalone persistent gather: no LDS, no barriers ----------------
__global__ __launch_bounds__(256) void gather_kernel(
    const unsigned short* __restrict__ feat,
    const int* __restrict__ row_ptr, const unsigned short* __restrict__ esrc,
    unsigned short* __restrict__ agg)
{
    const int tid = threadIdx.x;
    const int wave = tid >> 6, lane = tid & 63;
    const int g = lane >> 4, c = lane & 15;
    const int gw0 = blockIdx.x * 4 + wave;
    const int NW = gridDim.x * 4;
    const int NGROUP = N_NODES / 4;   // 12500

    for (int grp = gw0; grp < NGROUP; grp += NW) {
        const int base = grp * 4;
        int beg[4], deg[4], ids[4];
        int rp0 = row_ptr[base];
        #pragma unroll
        for (int j = 0; j < 4; ++j) {
            int rp1 = row_ptr[base + j + 1];
            beg[j] = rp0; deg[j] = rp1 - rp0; rp0 = rp1;
        }
        #pragma unroll
        for (int j = 0; j < 4; ++j) {
            int idx = beg[j] + c;
            idx = (idx < N_EDGES) ? idx : (N_EDGES - 1);
            ids[j] = esrc[idx];
        }

        float acc[4][8];
        #pragma unroll
        for (int j = 0; j < 4; ++j)
            #pragma unroll
            for (int k = 0; k < 8; ++k) acc[j][k] = 0.0f;

        #pragma unroll
        for (int jp = 0; jp < 2; ++jp) {
            uint4 v[2][4];
            #pragma unroll
            for (int jj = 0; jj < 2; ++jj) {
                const int j = jp * 2 + jj;
                #pragma unroll
                for (int b = 0; b < 4; ++b) {
                    int s = __shfl(ids[j], b * 4 + g);
                    v[jj][b] = *reinterpret_cast<const uint4*>(feat + (size_t)s * HID + c * 8);
                }
            }
            #pragma unroll
            for (int jj = 0; jj < 2; ++jj) {
                const int j = jp * 2 + jj;
                #pragma unroll
                for (int b = 0; b < 4; ++b) {
                    uint4 vv = v[jj][b];
                    if (b * 4 + g >= deg[j]) vv = make_uint4(0u, 0u, 0u, 0u);
                    acc_u4(acc[j], vv);
                }
            }
            #pragma unroll
            for (int jj = 0; jj < 2; ++jj) {
                const int j = jp * 2 + jj;
                const int last = beg[j] + deg[j] - 1;
                for (int e0 = 16; e0 < deg[j]; e0 += 16) {
                    int idx = beg[j] + e0 + c;
                    int id2 = esrc[(idx < last) ? idx : last];
                    uint4 w[4];
                    #pragma unroll
                    for (int b = 0; b < 4; ++b) {
                        int s = __shfl(id2, b * 4 + g);
                        w[b] = *reinterpret_cast<const uint4*>(feat + (size_t)s * HID + c * 8);
                    }
                    #pragma unroll
                    for (int b = 0; b < 4; ++b) {
                        uint4 vv = w[b];
                        if (e0 + b * 4 + g >= deg[j]) vv = make_uint4(0u, 0u, 0u, 0u);
                        acc_u4(acc[j], vv);
                    }
                }
            }
        }

        #pragma unroll
        for (int j = 0; j < 4; ++j) {
            const float scale = 1.0f / fmaxf((float)deg[j], 1.0f);
            float r[8];
            #pragma unroll
            for (int k = 0; k < 8; ++k) {
                float t = acc[j][k];
                t += __shfl_xor(t, 16);
                t += __shfl_xor(t, 32);
                r[k] = t * scale;
            }
            if (g == 0) {
                uint4 pk;
                pk.x = (unsigned)f2bf(r[0]) | ((unsigned)f2bf(r[1]) << 16);
                pk.y = (unsigned)f2bf(r[2]) | ((unsigned)f2bf(r[3]) << 16);
                pk.z = (unsigned)f2bf(r[4]) | ((unsigned)f2bf(r[5]) << 16);
                pk.w = (unsigned)f2bf(r[6]) | ((unsigned)f2bf(r[7]) << 16);
                *reinterpret_cast<uint4*>(agg + (size_t)(base + j) * HID + c * 8) = pk;
            }
        }
    }
}

// ---------------- streaming SAGE GEMM (fragment-ordered weights) ----------------
__global__ __launch_bounds__(256) void sage_gemm_kernel(
    const unsigned short* __restrict__ aggIn,
    const unsigned short* __restrict__ selfIn,
    const unsigned short* __restrict__ wsz,
    const float* __restrict__ bias,
    unsigned short* __restrict__ Hout, int relu)
{
    __shared__ unsigned short sA[16 * LDA];
    const int tid = threadIdx.x;
    const int wave = tid >> 6, lane = tid & 63;
    const int m0 = blockIdx.x * 16;

    {
        int r = tid >> 4, cc = tid & 15;
        *reinterpret_cast<uint4*>(&sA[r * LDA + cc * 8]) =
            reinterpret_cast<const uint4*>(aggIn + (size_t)(m0 + r) * HID)[cc];
        *reinterpret_cast<uint4*>(&sA[r * LDA + 128 + cc * 8]) =
            reinterpret_cast<const uint4*>(selfIn + (size_t)(m0 + r) * HID)[cc];
    }
    __syncthreads();

    const int l15 = lane & 15, lq = lane >> 4;
    bf16x8 bfrag[2][8];
    #pragma unroll
    for (int nt = 0; nt < 2; ++nt) {
        const unsigned short* wb = wsz + ((size_t)(wave * 2 + nt) * 8) * 64 * 8 + lane * 8;
        #pragma unroll
        for (int ks = 0; ks < 8; ++ks)
            bfrag[nt][ks] = *reinterpret_cast<const bf16x8*>(wb + (size_t)ks * 64 * 8);
    }
    f32x4 acc0 = {0.f, 0.f, 0.f, 0.f}, acc1 = {0.f, 0.f, 0.f, 0.f};
    #pragma unroll
    for (int ks = 0; ks < 8; ++ks) {
        bf16x8 af = *reinterpret_cast<const bf16x8*>(&sA[l15 * LDA + ks * 32 + lq * 8]);
        acc0 = __builtin_amdgcn_mfma_f32_16x16x32_bf16(af, bfrag[0][ks], acc0, 0, 0, 0);
        acc1 = __builtin_amdgcn_mfma_f32_16x16x32_bf16(af, bfrag[1][ks], acc1, 0, 0, 0);
    }
    const int n0 = wave * 32;
    #pragma unroll
    for (int nt = 0; nt < 2; ++nt) {
        const f32x4 a = nt ? acc1 : acc0;
        const int col = n0 + nt * 16 + l15;
        const float bv = bias[col];
        #pragma unroll
        for (int r = 0; r < 4; ++r) {
            float v = a[r] + bv;
            if (relu) v = fmaxf(v, 0.0f);
            Hout[(size_t)(m0 + lq * 4 + r) * HID + col] = f2bf(v);
        }
    }
}

// ---------------- layer-2 GEMM + MFMA head + log_softmax ----------------
__global__ __launch_bounds__(256) void final_gemm_kernel(
    const unsigned short* __restrict__ aggIn,
    const unsigned short* __restrict__ selfIn,
    const unsigned short* __restrict__ wsz2,
    const float* __restrict__ bl2,
    const unsigned short* __restrict__ wos,
    const float* __restrict__ bout,
    float* __restrict__ out)
{
    __shared__ unsigned short sA[16 * LDA];     // 8448 B
    __shared__ float sL[16][OUT_CH];            // 4096 B
    const int tid = threadIdx.x;
    const int wave = tid >> 6, lane = tid & 63;
    const int m0 = blockIdx.x * 16;

    {
        int r = tid >> 4, cc = tid & 15;
        *reinterpret_cast<uint4*>(&sA[r * LDA + cc * 8]) =
            reinterpret_cast<const uint4*>(aggIn + (size_t)(m0 + r) * HID)[cc];
        *reinterpret_cast<uint4*>(&sA[r * LDA + 128 + cc * 8]) =
            reinterpret_cast<const uint4*>(selfIn + (size_t)(m0 + r) * HID)[cc];
    }
    __syncthreads();

    const int l15 = lane & 15, lq = lane >> 4;
    bf16x8 bfrag[2][8];
    #pragma unroll
    for (int nt = 0; nt < 2; ++nt) {
        const unsigned short* wb = wsz2 + ((size_t)(wave * 2 + nt) * 8) * 64 * 8 + lane * 8;
        #pragma unroll
        for (int ks = 0; ks < 8; ++ks)
            bfrag[nt][ks] = *reinterpret_cast<const bf16x8*>(wb + (size_t)ks * 64 * 8);
    }
    f32x4 acc0 = {0.f, 0.f, 0.f, 0.f}, acc1 = {0.f, 0.f, 0.f, 0.f};
    #pragma unroll
    for (int ks = 0; ks < 8; ++ks) {
        bf16x8 af = *reinterpret_cast<const bf16x8*>(&sA[l15 * LDA + ks * 32 + lq * 8]);
        acc0 = __builtin_amdgcn_mfma_f32_16x16x32_bf16(af, bfrag[0][ks], acc0, 0, 0, 0);
        acc1 = __builtin_amdgcn_mfma_f32_16x16x32_bf16(af, bfrag[1][ks], acc1, 0, 0, 0);
    }
    __syncthreads();   // all waves done reading sA before h2 overwrite

    const int n0 = wave * 32;
    #pragma unroll
    for (int nt = 0; nt < 2; ++nt) {
        const f32x4 a = nt ? acc1 : acc0;
        const int col = n0 + nt * 16 + l15;
        const float bv = bl2[col];
        #pragma unroll
        for (int r = 0; r < 4; ++r)
            sA[(lq * 4 + r) * LDA + col] = f2bf(a[r] + bv);
    }
    __syncthreads();

    {
        f32x4 hacc = {0.f, 0.f, 0.f, 0.f};
        #pragma unroll
        for (int ks = 0; ks < 4; ++ks) {
            bf16x8 af = *reinterpret_cast<const bf16x8*>(&sA[l15 * LDA + ks * 32 + lq * 8]);
            bf16x8 bf = *reinterpret_cast<const bf16x8*>(
                wos + ((size_t)(wave * 4 + ks)) * 64 * 8 + lane * 8);
            hacc = __builtin_amdgcn_mfma_f32_16x16x32_bf16(af, bf, hacc, 0, 0, 0);
        }
        const int col = wave * 16 + l15;
        const float bo = bout[col];
        #pragma unroll
        for (int r = 0; r < 4; ++r)
            sL[lq * 4 + r][col] = hacc[r] + bo;
    }
    __syncthreads();

    for (int r = wave; r < 16; r += 4) {
        float v = sL[r][lane];
        float m = v;
        for (int off = 32; off; off >>= 1) m = fmaxf(m, __shfl_xor(m, off));
        float ex = expf(v - m);
        float s = ex;
        for (int off = 32; off; off >>= 1) s += __shfl_xor(s, off);
        out[(size_t)(m0 + r) * OUT_CH + lane] = v - m - logf(s);
    }
}

extern "C" void kernel_launch(void* const* d_in, const int* in_sizes, int n_in,
                              void* d_out, int out_size, void* d_ws, size_t ws_size,
                              hipStream_t stream) {
    const float* x    = (const float*)d_in[0];
    const int*   edge = (const int*)d_in[1];
    const int*   src  = edge;
    const int*   dst  = edge + N_EDGES;
    const float* Wl1  = (const float*)d_in[2];
    const float* bl1  = (const float*)d_in[3];
    const float* Wr1  = (const float*)d_in[4];
    const float* Wl2  = (const float*)d_in[5];
    const float* bl2  = (const float*)d_in[6];
    const float* Wr2  = (const float*)d_in[7];
    const float* Wout = (const float*)d_in[8];
    const float* bout = (const float*)d_in[9];
    float* out = (float*)d_out;

    char* ws = (char*)d_ws;
    const size_t featBytes = (size_t)N_NODES * HID * 2;          // 12.8 MB
    unsigned short* xb  = (unsigned short*)ws;
    unsigned short* h1  = (unsigned short*)(ws + featBytes);
    unsigned short* agg = (unsigned short*)(ws + 2 * featBytes);
    char* p = ws + 3 * featBytes;
    int* row_ptr = (int*)p;          p += (size_t)(N_NODES + 1) * 4 + 252;
    int* histg   = (int*)p;          p += (size_t)NBUCKET * NCHUNK * 4;   // 800,768 B
    int* partial = (int*)p;          p += (size_t)NBUCKET * 4 + 72;
    unsigned* epack = (unsigned*)p;  p += (size_t)N_EDGES * 4;            // 3.2 MB
    unsigned short* esrc = (unsigned short*)p;  p += (size_t)N_EDGES * 2; // 1.6 MB
    unsigned short* w1s = (unsigned short*)p;   p += 128 * 256 * 2;       // 64 KB
    unsigned short* w2s = (unsigned short*)p;   p += 128 * 256 * 2;       // 64 KB
    unsigned short* wos = (unsigned short*)p;                             // 16 KB

    convert_x_kernel<<<N_NODES * 32 / 256, 256, 0, stream>>>(x, xb);
    swizzle_w_kernel<<<36, 256, 0, stream>>>(Wl1, Wr1, Wl2, Wr2, Wout, w1s, w2s, wos);
    histb_kernel<<<NCHUNK, 256, 0, stream>>>(dst, histg);
    scanA2_kernel<<<NBUCKET, 256, 0, stream>>>(histg, partial);
    scanB2_kernel<<<1, 256, 0, stream>>>(partial);
    scanC2_kernel<<<NBUCKET, 256, 0, stream>>>(histg, partial);
    binA_kernel<<<NCHUNK, 256, 0, stream>>>(src, dst, histg, epack);
    bucket_sort_kernel<<<NBUCKET, 256, 0, stream>>>(epack, histg, row_ptr, esrc);

    gather_kernel<<<2048, 256, 0, stream>>>(xb, row_ptr, esrc, agg);
    sage_gemm_kernel<<<N_NODES / 16, 256, 0, stream>>>(agg, xb, w1s, bl1, h1, 1);
    gather_kernel<<<2048, 256, 0, stream>>>(h1, row_ptr, esrc, agg);
    final_gemm_kernel<<<N_NODES / 16, 256, 0, stream>>>(agg, h1, w2s, bl2,
                                                        wos, bout, out);
}

// Round 13
// 131.949 us; speedup vs baseline: 2.7575x; 1.0087x over previous
//
#include <hip/hip_runtime.h>

#define N_NODES 50000
#define N_EDGES 800000
#define HID 128
#define OUT_CH 64
#define LDA 264   // LDS A-tile row stride in bf16 elems (256 + 8 pad)
#define BSHIFT 6
#define NBUCKET ((N_NODES + 63) >> BSHIFT)   // 782
#define NCHUNK 256
#define CHUNK_E (N_EDGES / NCHUNK)           // 3125
#define BCAP 2560
#define GATHER_BLOCKS 1563                   // 6252 waves x 2 groups = 12504 >= 12500

typedef __attribute__((ext_vector_type(8))) short bf16x8;
typedef __attribute__((ext_vector_type(4))) float f32x4;

__device__ __forceinline__ float bf2f(unsigned int bits16) {
    return __uint_as_float(bits16 << 16);
}
__device__ __forceinline__ unsigned short f2bf(float f) {
    unsigned int u = __float_as_uint(f);
    u = (u + 0x7fffu + ((u >> 16) & 1u)) >> 16;
    return (unsigned short)u;
}
__device__ __forceinline__ void acc_u4(float* a, uint4 v) {
    a[0] += bf2f(v.x & 0xffffu); a[1] += bf2f(v.x >> 16);
    a[2] += bf2f(v.y & 0xffffu); a[3] += bf2f(v.y >> 16);
    a[4] += bf2f(v.z & 0xffffu); a[5] += bf2f(v.z >> 16);
    a[6] += bf2f(v.w & 0xffffu); a[7] += bf2f(v.w >> 16);
}

// ---------------- fp8 e4m3fn encode (cold path) ----------------
__device__ __forceinline__ unsigned int f2fp8(float f) {
    unsigned int u = __float_as_uint(f);
    unsigned int s = (u >> 24) & 0x80u;
    float xa = fabsf(f);
    if (xa >= 0.015625f) {
        unsigned int a = __float_as_uint(xa);
        if (a > 0x43E00000u) a = 0x43E00000u;                 // clamp to 448
        unsigned int r = a + 0x0007FFFFu + ((a >> 20) & 1u);  // RNE to 3 mant bits
        unsigned int e8 = r >> 23;
        if (e8 > 135u) { r = 0x43E00000u; e8 = 135u; }
        return s | (((e8 - 120u) << 3) | ((r >> 20) & 7u));
    } else {
        int q = (int)(xa * 512.0f + 0.5f);
        return s | (unsigned int)q;
    }
}
// ---------------- fp8 e4m3fn decode-accumulate (hot path) ----------------
__device__ __forceinline__ void acc_fp8x4(float* a, unsigned int u) {
#if __has_builtin(__builtin_amdgcn_cvt_pk_f32_fp8)
    auto p0 = __builtin_amdgcn_cvt_pk_f32_fp8(u, false);
    auto p1 = __builtin_amdgcn_cvt_pk_f32_fp8(u, true);
    a[0] += p0[0]; a[1] += p0[1]; a[2] += p1[0]; a[3] += p1[1];
#else
    #pragma unroll
    for (int i = 0; i < 4; ++i) {
        unsigned int b = (u >> (8 * i)) & 0xffu;
        float d = __uint_as_float(((b & 0x7fu) << 20) | ((b & 0x80u) << 24));
        a[i] = fmaf(d, 0x1p120f, a[i]);
    }
#endif
}

// ---------------- prep: x -> bf16 + fp8; weights -> fragment order ----------------
__global__ __launch_bounds__(256) void prep_kernel(
    const float* __restrict__ x, unsigned short* __restrict__ xb,
    unsigned char* __restrict__ x8,
    const float* __restrict__ Wl1, const float* __restrict__ Wr1,
    const float* __restrict__ Wl2, const float* __restrict__ Wr2,
    const float* __restrict__ Wout,
    unsigned short* __restrict__ w1s, unsigned short* __restrict__ w2s,
    unsigned short* __restrict__ wos)
{
    const int XB = N_NODES * 32 / 256;   // 6250
    const int b = blockIdx.x;
    if (b < XB) {
        int gid = b * 256 + threadIdx.x;
        int node = gid >> 5, c4 = gid & 31;
        float4 v = reinterpret_cast<const float4*>(x + (size_t)node * HID)[c4];
        unsigned short* o = xb + (size_t)node * HID + c4 * 4;
        o[0] = f2bf(v.x); o[1] = f2bf(v.y); o[2] = f2bf(v.z); o[3] = f2bf(v.w);
        unsigned int pk8 = f2fp8(v.x) | (f2fp8(v.y) << 8) | (f2fp8(v.z) << 16) | (f2fp8(v.w) << 24);
        *reinterpret_cast<unsigned int*>(x8 + (size_t)node * HID + c4 * 4) = pk8;
    } else {
        int fid = (b - XB) * 256 + threadIdx.x;   // 0..9215
        if (fid < 8192) {
            int layer = fid >> 12;
            int r = fid & 4095;
            int lane = r & 63, ks = (r >> 6) & 7, t = r >> 9;
            int col = t * 16 + (lane & 15);
            int kb = ks * 32 + (lane >> 4) * 8;
            const float* Wl = layer ? Wl2 : Wl1;
            const float* Wr = layer ? Wr2 : Wr1;
            unsigned short* o = (layer ? w2s : w1s) + (size_t)r * 8;
            #pragma unroll
            for (int j = 0; j < 8; ++j) {
                int k = kb + j;
                float v = (k < 128) ? Wl[(size_t)col * 128 + k] : Wr[(size_t)col * 128 + (k - 128)];
                o[j] = f2bf(v);
            }
        } else if (fid < 9216) {
            int r = fid - 8192;
            int lane = r & 63, ks = (r >> 6) & 3, t = r >> 8;
            int col = t * 16 + (lane & 15);
            int kb = ks * 32 + (lane >> 4) * 8;
            unsigned short* o = wos + (size_t)r * 8;
            #pragma unroll
            for (int j = 0; j < 8; ++j)
                o[j] = f2bf(Wout[(size_t)col * 128 + kb + j]);
        }
    }
}

// ---------------- stage 1: per-chunk bucket histogram (LDS counters) ----------------
__global__ __launch_bounds__(256) void histb_kernel(const int* __restrict__ dst,
                                                    int* __restrict__ histg) {
    __shared__ int h[NBUCKET];
    for (int i = threadIdx.x; i < NBUCKET; i += 256) h[i] = 0;
    __syncthreads();
    const int e0 = blockIdx.x * CHUNK_E;
    for (int i = threadIdx.x; i < CHUNK_E; i += 256)
        atomicAdd(&h[dst[e0 + i] >> BSHIFT], 1);
    __syncthreads();
    for (int i = threadIdx.x; i < NBUCKET; i += 256)
        histg[i * NCHUNK + blockIdx.x] = h[i];
}

// ---------------- stage 2: exclusive scan over histg ----------------
__global__ __launch_bounds__(256) void scanA2_kernel(const int* __restrict__ histg,
                                                     int* __restrict__ partial) {
    const int tid = threadIdx.x;
    int v = histg[blockIdx.x * 256 + tid];
    const int lane = tid & 63, wave = tid >> 6;
    int incl = v;
    #pragma unroll
    for (int off = 1; off < 64; off <<= 1) {
        int t = __shfl_up(incl, off);
        if (lane >= off) incl += t;
    }
    __shared__ int wsum[4];
    if (lane == 63) wsum[wave] = incl;
    __syncthreads();
    if (tid == 0) partial[blockIdx.x] = wsum[0] + wsum[1] + wsum[2] + wsum[3];
}

__global__ __launch_bounds__(256) void scanB2_kernel(int* __restrict__ partial) {
    const int tid = threadIdx.x;
    int vals[4]; int sum = 0;
    #pragma unroll
    for (int j = 0; j < 4; ++j) {
        int idx = tid * 4 + j;
        vals[j] = (idx < NBUCKET) ? partial[idx] : 0;
        sum += vals[j];
    }
    const int lane = tid & 63, wave = tid >> 6;
    int incl = sum;
    #pragma unroll
    for (int off = 1; off < 64; off <<= 1) {
        int t = __shfl_up(incl, off);
        if (lane >= off) incl += t;
    }
    __shared__ int wsum[4];
    if (lane == 63) wsum[wave] = incl;
    __syncthreads();
    int base = 0;
    if (wave > 0) base += wsum[0];
    if (wave > 1) base += wsum[1];
    if (wave > 2) base += wsum[2];
    int run = base + incl - sum;
    #pragma unroll
    for (int j = 0; j < 4; ++j) {
        int idx = tid * 4 + j;
        if (idx < NBUCKET) { int c = vals[j]; partial[idx] = run; run += c; }
    }
}

__global__ __launch_bounds__(256) void scanC2_kernel(int* __restrict__ histg,
                                                     const int* __restrict__ partial) {
    const int tid = threadIdx.x;
    const int i = blockIdx.x * 256 + tid;
    int v = histg[i];
    const int lane = tid & 63, wave = tid >> 6;
    int incl = v;
    #pragma unroll
    for (int off = 1; off < 64; off <<= 1) {
        int t = __shfl_up(incl, off);
        if (lane >= off) incl += t;
    }
    __shared__ int wsum[4];
    if (lane == 63) wsum[wave] = incl;
    __syncthreads();
    int base = partial[blockIdx.x];
    if (wave > 0) base += wsum[0];
    if (wave > 1) base += wsum[1];
    if (wave > 2) base += wsum[2];
    histg[i] = base + incl - v;
}

// ---------------- stage 3: bin edges into bucket regions ----------------
__global__ __launch_bounds__(256) void binA_kernel(
    const int* __restrict__ src, const int* __restrict__ dst,
    const int* __restrict__ obase, unsigned* __restrict__ epack)
{
    __shared__ int cur[NBUCKET];
    for (int i = threadIdx.x; i < NBUCKET; i += 256)
        cur[i] = obase[i * NCHUNK + blockIdx.x];
    __syncthreads();
    const int e0 = blockIdx.x * CHUNK_E;
    for (int i = threadIdx.x; i < CHUNK_E; i += 256) {
        int d = dst[e0 + i];
        int p = atomicAdd(&cur[d >> BSHIFT], 1);
        epack[p] = (unsigned)src[e0 + i] | ((unsigned)(d & 63) << 16);
    }
}

// ---------------- stage 4: in-LDS bucket sort -> esrc (ushort) + row_ptr ----------------
__global__ __launch_bounds__(256) void bucket_sort_kernel(
    const unsigned* __restrict__ epack, const int* __restrict__ obase,
    int* __restrict__ row_ptr, unsigned short* __restrict__ esrc)
{
    __shared__ unsigned lpack[BCAP];
    __shared__ unsigned short lout[BCAP];
    __shared__ int deg[64], cur[64];
    const int b = blockIdx.x;
    const int tid = threadIdx.x;
    const int regBeg = obase[b * NCHUNK];
    const int regEnd = (b + 1 < NBUCKET) ? obase[(b + 1) * NCHUNK] : N_EDGES;
    const int cnt = regEnd - regBeg;

    if (tid < 64) deg[tid] = 0;
    __syncthreads();
    for (int i = tid; i < cnt; i += 256) {
        unsigned p = epack[regBeg + i];
        if (i < BCAP) lpack[i] = p;
        atomicAdd(&deg[(p >> 16) & 63], 1);
    }
    __syncthreads();
    if (tid < 64) {
        int v = deg[tid];
        int incl = v;
        #pragma unroll
        for (int off = 1; off < 64; off <<= 1) {
            int t = __shfl_up(incl, off);
            if (tid >= off) incl += t;
        }
        int pre = incl - v;
        cur[tid] = pre;
        int node = b * 64 + tid;
        if (node < N_NODES) row_ptr[node] = regBeg + pre;
    }
    if (b == NBUCKET - 1 && tid == 0) row_ptr[N_NODES] = N_EDGES;
    __syncthreads();
    for (int i = tid; i < cnt; i += 256) {
        unsigned p = (i < BCAP) ? lpack[i] : epack[regBeg + i];
        int q = atomicAdd(&cur[(p >> 16) & 63], 1);
        unsigned short s = (unsigned short)(p & 0xffffu);
        if (q < BCAP) lout[q] = s;
        else esrc[regBeg + q] = s;
    }
    __syncthreads();
    const int lim = (cnt < BCAP) ? cnt : BCAP;
    for (int i = tid; i < lim; i += 256)
        esrc[regBeg + i] = lout[i];
}

// ---------------- persistent bf16 gather (layer 2) ----------------
__global__ __launch_bounds__(256) void gather_kernel(
    const unsigned short* __restrict__ feat,
    const int* __restrict__ row_ptr, const unsigned short* __restrict__ esrc,
    unsigned short* __restrict__ agg)
{
    const int tid = threadIdx.x;
    const int wave = tid >> 6, lane = tid & 63;
    const int g = lane >> 4, c = lane & 15;
    const int gw0 = blockIdx.x * 4 + wave;
    const int NW = gridDim.x * 4;
    const int NGROUP = N_NODES / 4;   // 12500

    for (int grp = gw0; grp < NGROUP; grp += NW) {
        const int base = grp * 4;
        int beg[4], deg[4], ids[4];
        int rp0 = row_ptr[base];
        #pragma unroll
        for (int j = 0; j < 4; ++j) {
            int rp1 = row_ptr[base + j + 1];
            beg[j] = rp0; deg[j] = rp1 - rp0; rp0 = rp1;
        }
        #pragma unroll
        for (int j = 0; j < 4; ++j) {
            int idx = beg[j] + c;
            idx = (idx < N_EDGES) ? idx : (N_EDGES - 1);
            ids[j] = esrc[idx];
        }

        float acc[4][8];
        #pragma unroll
        for (int j = 0; j < 4; ++j)
            #pragma unroll
            for (int k = 0; k < 8; ++k) acc[j][k] = 0.0f;

        #pragma unroll
        for (int jp = 0; jp < 2; ++jp) {
            uint4 v[2][4];
            #pragma unroll
            for (int jj = 0; jj < 2; ++jj) {
                const int j = jp * 2 + jj;
                #pragma unroll
                for (int b = 0; b < 4; ++b) {
                    int s = __shfl(ids[j], b * 4 + g);
                    v[jj][b] = *reinterpret_cast<const uint4*>(feat + (size_t)s * HID + c * 8);
                }
            }
            #pragma unroll
            for (int jj = 0; jj < 2; ++jj) {
                const int j = jp * 2 + jj;
                #pragma unroll
                for (int b = 0; b < 4; ++b) {
                    uint4 vv = v[jj][b];
                    if (b * 4 + g >= deg[j]) vv = make_uint4(0u, 0u, 0u, 0u);
                    acc_u4(acc[j], vv);
                }
            }
            #pragma unroll
            for (int jj = 0; jj < 2; ++jj) {
                const int j = jp * 2 + jj;
                const int last = beg[j] + deg[j] - 1;
                for (int e0 = 16; e0 < deg[j]; e0 += 16) {
                    int idx = beg[j] + e0 + c;
                    int id2 = esrc[(idx < last) ? idx : last];
                    uint4 w[4];
                    #pragma unroll
                    for (int b = 0; b < 4; ++b) {
                        int s = __shfl(id2, b * 4 + g);
                        w[b] = *reinterpret_cast<const uint4*>(feat + (size_t)s * HID + c * 8);
                    }
                    #pragma unroll
                    for (int b = 0; b < 4; ++b) {
                        uint4 vv = w[b];
                        if (e0 + b * 4 + g >= deg[j]) vv = make_uint4(0u, 0u, 0u, 0u);
                        acc_u4(acc[j], vv);
                    }
                }
            }
        }

        #pragma unroll
        for (int j = 0; j < 4; ++j) {
            const float scale = 1.0f / fmaxf((float)deg[j], 1.0f);
            float r[8];
            #pragma unroll
            for (int k = 0; k < 8; ++k) {
                float t = acc[j][k];
                t += __shfl_xor(t, 16);
                t += __shfl_xor(t, 32);
                r[k] = t * scale;
            }
            if (g == 0) {
                uint4 pk;
                pk.x = (unsigned)f2bf(r[0]) | ((unsigned)f2bf(r[1]) << 16);
                pk.y = (unsigned)f2bf(r[2]) | ((unsigned)f2bf(r[3]) << 16);
                pk.z = (unsigned)f2bf(r[4]) | ((unsigned)f2bf(r[5]) << 16);
                pk.w = (unsigned)f2bf(r[6]) | ((unsigned)f2bf(r[7]) << 16);
                *reinterpret_cast<uint4*>(agg + (size_t)(base + j) * HID + c * 8) = pk;
            }
        }
    }
}

// ---------------- persistent fp8 gather (layer 1): 128 B rows, 1 line each ----------------
__global__ __launch_bounds__(256) void gather_fp8_kernel(
    const unsigned char* __restrict__ feat8,
    const int* __restrict__ row_ptr, const unsigned short* __restrict__ esrc,
    unsigned short* __restrict__ agg)
{
    const int tid = threadIdx.x;
    const int wave = tid >> 6, lane = tid & 63;
    const int g = lane >> 4, c = lane & 15;
    const int gw0 = blockIdx.x * 4 + wave;
    const int NW = gridDim.x * 4;
    const int NGROUP = N_NODES / 4;

    for (int grp = gw0; grp < NGROUP; grp += NW) {
        const int base = grp * 4;
        int beg[4], deg[4], ids[4];
        int rp0 = row_ptr[base];
        #pragma unroll
        for (int j = 0; j < 4; ++j) {
            int rp1 = row_ptr[base + j + 1];
            beg[j] = rp0; deg[j] = rp1 - rp0; rp0 = rp1;
        }
        #pragma unroll
        for (int j = 0; j < 4; ++j) {
            int idx = beg[j] + c;
            idx = (idx < N_EDGES) ? idx : (N_EDGES - 1);
            ids[j] = esrc[idx];
        }

        float acc[4][8];
        #pragma unroll
        for (int j = 0; j < 4; ++j)
            #pragma unroll
            for (int k = 0; k < 8; ++k) acc[j][k] = 0.0f;

        #pragma unroll
        for (int jp = 0; jp < 2; ++jp) {
            uint2 v[2][4];
            #pragma unroll
            for (int jj = 0; jj < 2; ++jj) {
                const int j = jp * 2 + jj;
                #pragma unroll
                for (int b = 0; b < 4; ++b) {
                    int s = __shfl(ids[j], b * 4 + g);
                    v[jj][b] = *reinterpret_cast<const uint2*>(feat8 + (size_t)s * HID + c * 8);
                }
            }
            #pragma unroll
            for (int jj = 0; jj < 2; ++jj) {
                const int j = jp * 2 + jj;
                #pragma unroll
                for (int b = 0; b < 4; ++b) {
                    uint2 vv = v[jj][b];
                    if (b * 4 + g >= deg[j]) vv = make_uint2(0u, 0u);
                    acc_fp8x4(&acc[j][0], vv.x);
                    acc_fp8x4(&acc[j][4], vv.y);
                }
            }
            #pragma unroll
            for (int jj = 0; jj < 2; ++jj) {
                const int j = jp * 2 + jj;
                const int last = beg[j] + deg[j] - 1;
                for (int e0 = 16; e0 < deg[j]; e0 += 16) {
                    int idx = beg[j] + e0 + c;
                    int id2 = esrc[(idx < last) ? idx : last];
                    uint2 w[4];
                    #pragma unroll
                    for (int b = 0; b < 4; ++b) {
                        int s = __shfl(id2, b * 4 + g);
                        w[b] = *reinterpret_cast<const uint2*>(feat8 + (size_t)s * HID + c * 8);
                    }
                    #pragma unroll
                    for (int b = 0; b < 4; ++b) {
                        uint2 vv = w[b];
                        if (e0 + b * 4 + g >= deg[j]) vv = make_uint2(0u, 0u);
                        acc_fp8x4(&acc[j][0], vv.x);
                        acc_fp8x4(&acc[j][4], vv.y);
                    }
                }
            }
        }

        #pragma unroll
        for (int j = 0; j < 4; ++j) {
            const float scale = 1.0f / fmaxf((float)deg[j], 1.0f);
            float r[8];
            #pragma unroll
            for (int k = 0; k < 8; ++k) {
                float t = acc[j][k];
                t += __shfl_xor(t, 16);
                t += __shfl_xor(t, 32);
                r[k] = t * scale;
            }
            if (g == 0) {
                uint4 pk;
                pk.x = (unsigned)f2bf(r[0]) | ((unsigned)f2bf(r[1]) << 16);
                pk.y = (unsigned)f2bf(r[2]) | ((unsigned)f2bf(r[3]) << 16);
                pk.z = (unsigned)f2bf(r[4]) | ((unsigned)f2bf(r[5]) << 16);
                pk.w = (unsigned)f2bf(r[6]) | ((unsigned)f2bf(r[7]) << 16);
                *reinterpret_cast<uint4*>(agg + (size_t)(base + j) * HID + c * 8) = pk;
            }
        }
    }
}

// ---------------- streaming SAGE GEMM (fragment-ordered weights) ----------------
__global__ __launch_bounds__(256) void sage_gemm_kernel(
    const unsigned short* __restrict__ aggIn,
    const unsigned short* __restrict__ selfIn,
    const unsigned short* __restrict__ wsz,
    const float* __restrict__ bias,
    unsigned short* __restrict__ Hout, int relu)
{
    __shared__ unsigned short sA[16 * LDA];
    const int tid = threadIdx.x;
    const int wave = tid >> 6, lane = tid & 63;
    const int m0 = blockIdx.x * 16;

    {
        int r = tid >> 4, cc = tid & 15;
        *reinterpret_cast<uint4*>(&sA[r * LDA + cc * 8]) =
            reinterpret_cast<const uint4*>(aggIn + (size_t)(m0 + r) * HID)[cc];
        *reinterpret_cast<uint4*>(&sA[r * LDA + 128 + cc * 8]) =
            reinterpret_cast<const uint4*>(selfIn + (size_t)(m0 + r) * HID)[cc];
    }
    __syncthreads();

    const int l15 = lane & 15, lq = lane >> 4;
    bf16x8 bfrag[2][8];
    #pragma unroll
    for (int nt = 0; nt < 2; ++nt) {
        const unsigned short* wb = wsz + ((size_t)(wave * 2 + nt) * 8) * 64 * 8 + lane * 8;
        #pragma unroll
        for (int ks = 0; ks < 8; ++ks)
            bfrag[nt][ks] = *reinterpret_cast<const bf16x8*>(wb + (size_t)ks * 64 * 8);
    }
    f32x4 acc0 = {0.f, 0.f, 0.f, 0.f}, acc1 = {0.f, 0.f, 0.f, 0.f};
    #pragma unroll
    for (int ks = 0; ks < 8; ++ks) {
        bf16x8 af = *reinterpret_cast<const bf16x8*>(&sA[l15 * LDA + ks * 32 + lq * 8]);
        acc0 = __builtin_amdgcn_mfma_f32_16x16x32_bf16(af, bfrag[0][ks], acc0, 0, 0, 0);
        acc1 = __builtin_amdgcn_mfma_f32_16x16x32_bf16(af, bfrag[1][ks], acc1, 0, 0, 0);
    }
    const int n0 = wave * 32;
    #pragma unroll
    for (int nt = 0; nt < 2; ++nt) {
        const f32x4 a = nt ? acc1 : acc0;
        const int col = n0 + nt * 16 + l15;
        const float bv = bias[col];
        #pragma unroll
        for (int r = 0; r < 4; ++r) {
            float v = a[r] + bv;
            if (relu) v = fmaxf(v, 0.0f);
            Hout[(size_t)(m0 + lq * 4 + r) * HID + col] = f2bf(v);
        }
    }
}

// ---------------- layer-2 GEMM + MFMA head + log_softmax ----------------
__global__ __launch_bounds__(256) void final_gemm_kernel(
    const unsigned short* __restrict__ aggIn,
    const unsigned short* __restrict__ selfIn,
    const unsigned short* __restrict__ wsz2,
    const float* __restrict__ bl2,
    const unsigned short* __restrict__ wos,
    const float* __restrict__ bout,
    float* __restrict__ out)
{
    __shared__ unsigned short sA[16 * LDA];
    __shared__ float sL[16][OUT_CH];
    const int tid = threadIdx.x;
    const int wave = tid >> 6, lane = tid & 63;
    const int m0 = blockIdx.x * 16;

    {
        int r = tid >> 4, cc = tid & 15;
        *reinterpret_cast<uint4*>(&sA[r * LDA + cc * 8]) =
            reinterpret_cast<const uint4*>(aggIn + (size_t)(m0 + r) * HID)[cc];
        *reinterpret_cast<uint4*>(&sA[r * LDA + 128 + cc * 8]) =
            reinterpret_cast<const uint4*>(selfIn + (size_t)(m0 + r) * HID)[cc];
    }
    __syncthreads();

    const int l15 = lane & 15, lq = lane >> 4;
    bf16x8 bfrag[2][8];
    #pragma unroll
    for (int nt = 0; nt < 2; ++nt) {
        const unsigned short* wb = wsz2 + ((size_t)(wave * 2 + nt) * 8) * 64 * 8 + lane * 8;
        #pragma unroll
        for (int ks = 0; ks < 8; ++ks)
            bfrag[nt][ks] = *reinterpret_cast<const bf16x8*>(wb + (size_t)ks * 64 * 8);
    }
    f32x4 acc0 = {0.f, 0.f, 0.f, 0.f}, acc1 = {0.f, 0.f, 0.f, 0.f};
    #pragma unroll
    for (int ks = 0; ks < 8; ++ks) {
        bf16x8 af = *reinterpret_cast<const bf16x8*>(&sA[l15 * LDA + ks * 32 + lq * 8]);
        acc0 = __builtin_amdgcn_mfma_f32_16x16x32_bf16(af, bfrag[0][ks], acc0, 0, 0, 0);
        acc1 = __builtin_amdgcn_mfma_f32_16x16x32_bf16(af, bfrag[1][ks], acc1, 0, 0, 0);
    }
    __syncthreads();

    const int n0 = wave * 32;
    #pragma unroll
    for (int nt = 0; nt < 2; ++nt) {
        const f32x4 a = nt ? acc1 : acc0;
        const int col = n0 + nt * 16 + l15;
        const float bv = bl2[col];
        #pragma unroll
        for (int r = 0; r < 4; ++r)
            sA[(lq * 4 + r) * LDA + col] = f2bf(a[r] + bv);
    }
    __syncthreads();

    {
        f32x4 hacc = {0.f, 0.f, 0.f, 0.f};
        #pragma unroll
        for (int ks = 0; ks < 4; ++ks) {
            bf16x8 af = *reinterpret_cast<const bf16x8*>(&sA[l15 * LDA + ks * 32 + lq * 8]);
            bf16x8 bf = *reinterpret_cast<const bf16x8*>(
                wos + ((size_t)(wave * 4 + ks)) * 64 * 8 + lane * 8);
            hacc = __builtin_amdgcn_mfma_f32_16x16x32_bf16(af, bf, hacc, 0, 0, 0);
        }
        const int col = wave * 16 + l15;
        const float bo = bout[col];
        #pragma unroll
        for (int r = 0; r < 4; ++r)
            sL[lq * 4 + r][col] = hacc[r] + bo;
    }
    __syncthreads();

    for (int r = wave; r < 16; r += 4) {
        float v = sL[r][lane];
        float m = v;
        for (int off = 32; off; off >>= 1) m = fmaxf(m, __shfl_xor(m, off));
        float ex = expf(v - m);
        float s = ex;
        for (int off = 32; off; off >>= 1) s += __shfl_xor(s, off);
        out[(size_t)(m0 + r) * OUT_CH + lane] = v - m - logf(s);
    }
}

extern "C" void kernel_launch(void* const* d_in, const int* in_sizes, int n_in,
                              void* d_out, int out_size, void* d_ws, size_t ws_size,
                              hipStream_t stream) {
    const float* x    = (const float*)d_in[0];
    const int*   edge = (const int*)d_in[1];
    const int*   src  = edge;
    const int*   dst  = edge + N_EDGES;
    const float* Wl1  = (const float*)d_in[2];
    const float* bl1  = (const float*)d_in[3];
    const float* Wr1  = (const float*)d_in[4];
    const float* Wl2  = (const float*)d_in[5];
    const float* bl2  = (const float*)d_in[6];
    const float* Wr2  = (const float*)d_in[7];
    const float* Wout = (const float*)d_in[8];
    const float* bout = (const float*)d_in[9];
    float* out = (float*)d_out;

    char* ws = (char*)d_ws;
    const size_t featBytes  = (size_t)N_NODES * HID * 2;     // 12.8 MB
    const size_t feat8Bytes = (size_t)N_NODES * HID;         // 6.4 MB
    unsigned short* xb  = (unsigned short*)ws;
    unsigned short* h1  = (unsigned short*)(ws + featBytes);
    unsigned short* agg = (unsigned short*)(ws + 2 * featBytes);
    unsigned char*  x8  = (unsigned char*)(ws + 3 * featBytes);
    char* p = ws + 3 * featBytes + feat8Bytes;
    int* row_ptr = (int*)p;          p += (size_t)(N_NODES + 1) * 4 + 252;
    int* histg   = (int*)p;          p += (size_t)NBUCKET * NCHUNK * 4;
    int* partial = (int*)p;          p += (size_t)NBUCKET * 4 + 72;
    unsigned* epack = (unsigned*)p;  p += (size_t)N_EDGES * 4;
    unsigned short* esrc = (unsigned short*)p;  p += (size_t)N_EDGES * 2;
    unsigned short* w1s = (unsigned short*)p;   p += 128 * 256 * 2;
    unsigned short* w2s = (unsigned short*)p;   p += 128 * 256 * 2;
    unsigned short* wos = (unsigned short*)p;

    prep_kernel<<<N_NODES * 32 / 256 + 36, 256, 0, stream>>>(
        x, xb, x8, Wl1, Wr1, Wl2, Wr2, Wout, w1s, w2s, wos);
    histb_kernel<<<NCHUNK, 256, 0, stream>>>(dst, histg);
    scanA2_kernel<<<NBUCKET, 256, 0, stream>>>(histg, partial);
    scanB2_kernel<<<1, 256, 0, stream>>>(partial);
    scanC2_kernel<<<NBUCKET, 256, 0, stream>>>(histg, partial);
    binA_kernel<<<NCHUNK, 256, 0, stream>>>(src, dst, histg, epack);
    bucket_sort_kernel<<<NBUCKET, 256, 0, stream>>>(epack, histg, row_ptr, esrc);

    gather_fp8_kernel<<<GATHER_BLOCKS, 256, 0, stream>>>(x8, row_ptr, esrc, agg);
    sage_gemm_kernel<<<N_NODES / 16, 256, 0, stream>>>(agg, xb, w1s, bl1, h1, 1);
    gather_kernel<<<GATHER_BLOCKS, 256, 0, stream>>>(h1, row_ptr, esrc, agg);
    final_gemm_kernel<<<N_NODES / 16, 256, 0, stream>>>(agg, h1, w2s, bl2,
                                                        wos, bout, out);
}